// Round 1
// baseline (502.067 us; speedup 1.0000x reference)
//
#include <hip/hip_runtime.h>
#include <hip/hip_bf16.h>

typedef __attribute__((ext_vector_type(8))) short short8;   // 8 x bf16 = 4 VGPRs
typedef __attribute__((ext_vector_type(4))) short sh4;      // 4 x bf16 = 8 bytes
typedef __attribute__((ext_vector_type(4))) float floatx4;  // MFMA C/D

// total ordering: larger value wins; tie -> smaller index wins (jax.lax.top_k)
__device__ __forceinline__ bool better(float va, int ia, float vb, int ib) {
    return (va > vb) || (va == vb && ia < ib);
}
__device__ __forceinline__ bool betterd(double va, int ia, double vb, int ib) {
    return (va > vb) || (va == vb && ia < ib);
}

__device__ __forceinline__ short bf16_rn(float f) {
    __hip_bfloat16 h = __float2bfloat16(f);   // round-to-nearest-even
    return *reinterpret_cast<short*>(&h);
}
__device__ __forceinline__ float bf16_up(short s) {
    return __uint_as_float(((unsigned)(unsigned short)s) << 16);
}

// split 8 fp32 into bf16 hi + bf16 lo fragments (a ~= hi + lo)
__device__ __forceinline__ void split8(float4 a, float4 b, short8& hi, short8& lo) {
    float v[8] = {a.x, a.y, a.z, a.w, b.x, b.y, b.z, b.w};
    #pragma unroll
    for (int i = 0; i < 8; ++i) {
        short h = bf16_rn(v[i]);
        hi[i] = h;
        lo[i] = bf16_rn(v[i] - bf16_up(h));
    }
}

#define MFMA(A, B, C) __builtin_amdgcn_mfma_f32_16x16x32_bf16((A), (B), (C), 0, 0, 0)

// ---------------------------------------------------------------------------
// Prep: split W (64x1024 fp32) into bf16 hi/lo once.  64 blocks x 256 thr x 4.
// Values identical to split8() on the fly -> main-path numerics unchanged.
// ---------------------------------------------------------------------------
__global__ __launch_bounds__(256)
void wsplit_kernel(const float* __restrict__ Wg,
                   short* __restrict__ whi,
                   short* __restrict__ wlo)
{
    const int i = blockIdx.x * 256 + threadIdx.x;       // 16384 float4s
    float4 v = reinterpret_cast<const float4*>(Wg)[i];
    float vv[4] = {v.x, v.y, v.z, v.w};
    sh4 h, l;
    #pragma unroll
    for (int j = 0; j < 4; ++j) {
        short hh = bf16_rn(vv[j]);
        h[j] = hh;
        l[j] = bf16_rn(vv[j] - bf16_up(hh));
    }
    reinterpret_cast<sh4*>(whi)[i] = h;
    reinterpret_cast<sh4*>(wlo)[i] = l;
}

// ---------------------------------------------------------------------------
// Main router, pre-split W variant.  Fully unrolled k-loop: all loads get
// immediate offsets so the scheduler can hoist several iterations ahead.
// ---------------------------------------------------------------------------
__global__ __launch_bounds__(256, 4)
void router_kernel(const float* __restrict__ tokens,
                   const int* __restrict__ tarr,
                   const float* __restrict__ bg,
                   float* __restrict__ out,
                   int* __restrict__ flagCount,
                   int* __restrict__ flagList,
                   int listCap,
                   const short* __restrict__ whi,
                   const short* __restrict__ wlo)
{
    __shared__ __align__(16) float gtile[64 * 64];   // 16 KB fp32 gate tile

    const int lane = threadIdx.x & 63;
    const int wave = threadIdx.x >> 6;
    const int c16  = lane & 15;   // expert-within-tile (B col) / token (A row)
    const int quad = lane >> 4;   // k-chunk selector

    const int tokenBase = blockIdx.x * 64;
    const int token     = tokenBase + wave * 16 + c16;

    const float4* ap = reinterpret_cast<const float4*>(tokens) + (size_t)token * 256 + quad * 2;
    const short8* whiV = reinterpret_cast<const short8*>(whi);
    const short8* wloV = reinterpret_cast<const short8*>(wlo);
    // short8 index for (expert e, kb, quad):  e*128 + kb*4 + quad
    const int w0 = (c16 +  0) * 128 + quad;
    const int w1 = (c16 + 16) * 128 + quad;
    const int w2 = (c16 + 32) * 128 + quad;
    const int w3 = (c16 + 48) * 128 + quad;

    floatx4 acc0 = {0.f, 0.f, 0.f, 0.f};
    floatx4 acc1 = acc0, acc2 = acc0, acc3 = acc0;

    #pragma unroll
    for (int kb = 0; kb < 32; ++kb) {   // 32 k-steps of K=32
        float4 a0 = ap[kb * 8];
        float4 a1 = ap[kb * 8 + 1];
        short8 h0 = whiV[w0 + kb * 4];
        short8 h1 = whiV[w1 + kb * 4];
        short8 h2 = whiV[w2 + kb * 4];
        short8 h3 = whiV[w3 + kb * 4];
        short8 l0 = wloV[w0 + kb * 4];
        short8 l1 = wloV[w1 + kb * 4];
        short8 l2 = wloV[w2 + kb * 4];
        short8 l3 = wloV[w3 + kb * 4];

        short8 ahi, alo;
        split8(a0, a1, ahi, alo);

        // same per-acc MFMA order as before -> bitwise-identical accumulation
        acc0 = MFMA(ahi, h0, acc0); acc0 = MFMA(alo, h0, acc0); acc0 = MFMA(ahi, l0, acc0);
        acc1 = MFMA(ahi, h1, acc1); acc1 = MFMA(alo, h1, acc1); acc1 = MFMA(ahi, l1, acc1);
        acc2 = MFMA(ahi, h2, acc2); acc2 = MFMA(alo, h2, acc2); acc2 = MFMA(ahi, l2, acc2);
        acc3 = MFMA(ahi, h3, acc3); acc3 = MFMA(alo, h3, acc3); acc3 = MFMA(ahi, l3, acc3);
    }

    const float b0f = bg[c16 +  0];
    const float b1f = bg[c16 + 16];
    const float b2f = bg[c16 + 32];
    const float b3f = bg[c16 + 48];

    const float tb  = (float)tarr[tokenBase >> 12];   // 4096 tokens per batch
    const float cap = 0.5f + 1.1f * (tb / 1000.0f);

    const float A1 = 0.85f;            // 1 - alpha, alpha = 0.15
    const float A2 = 0.15f / 64.0f;    // alpha / E

    #pragma unroll
    for (int r = 0; r < 4; ++r) {
        float l0 = acc0[r] + b0f;
        float l1 = acc1[r] + b1f;
        float l2 = acc2[r] + b2f;
        float l3 = acc3[r] + b3f;

        // --- softmax over 64 experts (16-lane group x 4 local) ---
        float mx = fmaxf(fmaxf(l0, l1), fmaxf(l2, l3));
        #pragma unroll
        for (int off = 8; off >= 1; off >>= 1)
            mx = fmaxf(mx, __shfl_xor(mx, off));

        float e0 = expf(l0 - mx), e1 = expf(l1 - mx);
        float e2 = expf(l2 - mx), e3 = expf(l3 - mx);
        float s = e0 + e1 + e2 + e3;
        #pragma unroll
        for (int off = 8; off >= 1; off >>= 1)
            s += __shfl_xor(s, off);
        float inv = 1.0f / s;

        // --- routing floor ---
        float p0 = A1 * (e0 * inv) + A2;
        float p1 = A1 * (e1 * inv) + A2;
        float p2 = A1 * (e2 * inv) + A2;
        float p3 = A1 * (e3 * inv) + A2;

        // --- hard cap with excess redistribution ---
        float x0 = fmaxf(p0 - cap, 0.f), x1 = fmaxf(p1 - cap, 0.f);
        float x2 = fmaxf(p2 - cap, 0.f), x3 = fmaxf(p3 - cap, 0.f);
        float m0 = p0 - x0, m1 = p1 - x1, m2 = p2 - x2, m3 = p3 - x3;
        float h0 = fmaxf(cap - m0, 0.f), h1 = fmaxf(cap - m1, 0.f);
        float h2 = fmaxf(cap - m2, 0.f), h3 = fmaxf(cap - m3, 0.f);
        float sx = x0 + x1 + x2 + x3;
        float sh = h0 + h1 + h2 + h3;
        #pragma unroll
        for (int off = 8; off >= 1; off >>= 1) {
            sx += __shfl_xor(sx, off);
            sh += __shfl_xor(sh, off);
        }
        sh = fmaxf(sh, 1e-8f);
        float sc = sx / sh;
        float c0 = m0 + sc * h0;
        float c1 = m1 + sc * h1;
        float c2 = m2 + sc * h2;
        float c3 = m3 + sc * h3;

        // --- top-2 (value desc, tie -> smaller expert index) ---
        const int iA = c16, iB = c16 + 16, iC = c16 + 32, iD = c16 + 48;
        float v1, v2; int j1, j2;
        if (better(c0, iA, c1, iB)) { v1 = c0; j1 = iA; v2 = c1; j2 = iB; }
        else                        { v1 = c1; j1 = iB; v2 = c0; j2 = iA; }
        if (better(c2, iC, v1, j1))      { v2 = v1; j2 = j1; v1 = c2; j1 = iC; }
        else if (better(c2, iC, v2, j2)) { v2 = c2; j2 = iC; }
        if (better(c3, iD, v1, j1))      { v2 = v1; j2 = j1; v1 = c3; j1 = iD; }
        else if (better(c3, iD, v2, j2)) { v2 = c3; j2 = iD; }

        #pragma unroll
        for (int off = 1; off < 16; off <<= 1) {
            float w1 = __shfl_xor(v1, off); int k1 = __shfl_xor(j1, off);
            float w2 = __shfl_xor(v2, off); int k2 = __shfl_xor(j2, off);
            if (better(w1, k1, v1, j1)) {
                if (better(v1, j1, w2, k2)) { v2 = v1; j2 = j1; }
                else                        { v2 = w2; j2 = k2; }
                v1 = w1; j1 = k1;
            } else if (better(w1, k1, v2, j2)) {
                v2 = w1; j2 = k1;
            }
        }

        float g0 = (iA == j1 || iA == j2) ? c0 : 0.f;
        float g1 = (iB == j1 || iB == j2) ? c1 : 0.f;
        float g2 = (iC == j1 || iC == j2) ? c2 : 0.f;
        float g3 = (iD == j1 || iD == j2) ? c3 : 0.f;

        // --- rank2 vs rank3 margin; flag uncertain tokens for fp64 repair ---
        float t0 = (iA == j1 || iA == j2) ? -3.0e38f : c0;
        float t1 = (iB == j1 || iB == j2) ? -3.0e38f : c1;
        float t2 = (iC == j1 || iC == j2) ? -3.0e38f : c2;
        float t3 = (iD == j1 || iD == j2) ? -3.0e38f : c3;
        float m3v = fmaxf(fmaxf(t0, t1), fmaxf(t2, t3));
        #pragma unroll
        for (int off = 8; off >= 1; off >>= 1)
            m3v = fmaxf(m3v, __shfl_xor(m3v, off));

        const int tl = wave * 16 + quad * 4 + r;   // token within block
        bool flag = ((v2 - m3v) < 1e-4f) || (sx > 0.0f);
        if (flag && c16 == 0) {
            int pos = atomicAdd(flagCount, 1);
            if (pos < listCap) flagList[pos] = tokenBase + tl;
        }

        gtile[tl * 64 + iA] = g0;
        gtile[tl * 64 + iB] = g1;
        gtile[tl * 64 + iC] = g2;
        gtile[tl * 64 + iD] = g3;
    }

    __syncthreads();

    const uint4* src = reinterpret_cast<const uint4*>(gtile);
    uint4* dst = reinterpret_cast<uint4*>(out + (size_t)tokenBase * 64);
    dst[threadIdx.x]       = src[threadIdx.x];
    dst[threadIdx.x + 256] = src[threadIdx.x + 256];
    dst[threadIdx.x + 512] = src[threadIdx.x + 512];
    dst[threadIdx.x + 768] = src[threadIdx.x + 768];
}

// ---------------------------------------------------------------------------
// Legacy router (inline W split) — fallback when workspace is too small for
// the pre-split W area.  Identical to the previously verified kernel.
// ---------------------------------------------------------------------------
__global__ __launch_bounds__(256, 4)
void router_kernel_legacy(const float* __restrict__ tokens,
                          const int* __restrict__ tarr,
                          const float* __restrict__ Wg,
                          const float* __restrict__ bg,
                          float* __restrict__ out,
                          int* __restrict__ flagCount,
                          int* __restrict__ flagList,
                          int listCap)
{
    __shared__ __align__(16) float gtile[64 * 64];

    const int lane = threadIdx.x & 63;
    const int wave = threadIdx.x >> 6;
    const int c16  = lane & 15;
    const int quad = lane >> 4;

    const int tokenBase = blockIdx.x * 64;
    const int token     = tokenBase + wave * 16 + c16;

    const float4* ap = reinterpret_cast<const float4*>(tokens) + (size_t)token * 256 + quad * 2;
    const float4* wp0 = reinterpret_cast<const float4*>(Wg) + (size_t)(c16 +  0) * 256 + quad * 2;
    const float4* wp1 = reinterpret_cast<const float4*>(Wg) + (size_t)(c16 + 16) * 256 + quad * 2;
    const float4* wp2 = reinterpret_cast<const float4*>(Wg) + (size_t)(c16 + 32) * 256 + quad * 2;
    const float4* wp3 = reinterpret_cast<const float4*>(Wg) + (size_t)(c16 + 48) * 256 + quad * 2;

    floatx4 acc0 = {0.f, 0.f, 0.f, 0.f};
    floatx4 acc1 = acc0, acc2 = acc0, acc3 = acc0;

    for (int kb = 0; kb < 32; ++kb) {
        short8 ahi, alo;
        split8(ap[kb * 8], ap[kb * 8 + 1], ahi, alo);
        {
            short8 whi, wlo;
            split8(wp0[kb * 8], wp0[kb * 8 + 1], whi, wlo);
            acc0 = MFMA(ahi, whi, acc0);
            acc0 = MFMA(alo, whi, acc0);
            acc0 = MFMA(ahi, wlo, acc0);
        }
        {
            short8 whi, wlo;
            split8(wp1[kb * 8], wp1[kb * 8 + 1], whi, wlo);
            acc1 = MFMA(ahi, whi, acc1);
            acc1 = MFMA(alo, whi, acc1);
            acc1 = MFMA(ahi, wlo, acc1);
        }
        {
            short8 whi, wlo;
            split8(wp2[kb * 8], wp2[kb * 8 + 1], whi, wlo);
            acc2 = MFMA(ahi, whi, acc2);
            acc2 = MFMA(alo, whi, acc2);
            acc2 = MFMA(ahi, wlo, acc2);
        }
        {
            short8 whi, wlo;
            split8(wp3[kb * 8], wp3[kb * 8 + 1], whi, wlo);
            acc3 = MFMA(ahi, whi, acc3);
            acc3 = MFMA(alo, whi, acc3);
            acc3 = MFMA(ahi, wlo, acc3);
        }
    }

    const float b0f = bg[c16 +  0];
    const float b1f = bg[c16 + 16];
    const float b2f = bg[c16 + 32];
    const float b3f = bg[c16 + 48];

    const float tb  = (float)tarr[tokenBase >> 12];
    const float cap = 0.5f + 1.1f * (tb / 1000.0f);

    const float A1 = 0.85f;
    const float A2 = 0.15f / 64.0f;

    #pragma unroll
    for (int r = 0; r < 4; ++r) {
        float l0 = acc0[r] + b0f;
        float l1 = acc1[r] + b1f;
        float l2 = acc2[r] + b2f;
        float l3 = acc3[r] + b3f;

        float mx = fmaxf(fmaxf(l0, l1), fmaxf(l2, l3));
        #pragma unroll
        for (int off = 8; off >= 1; off >>= 1)
            mx = fmaxf(mx, __shfl_xor(mx, off));

        float e0 = expf(l0 - mx), e1 = expf(l1 - mx);
        float e2 = expf(l2 - mx), e3 = expf(l3 - mx);
        float s = e0 + e1 + e2 + e3;
        #pragma unroll
        for (int off = 8; off >= 1; off >>= 1)
            s += __shfl_xor(s, off);
        float inv = 1.0f / s;

        float p0 = A1 * (e0 * inv) + A2;
        float p1 = A1 * (e1 * inv) + A2;
        float p2 = A1 * (e2 * inv) + A2;
        float p3 = A1 * (e3 * inv) + A2;

        float x0 = fmaxf(p0 - cap, 0.f), x1 = fmaxf(p1 - cap, 0.f);
        float x2 = fmaxf(p2 - cap, 0.f), x3 = fmaxf(p3 - cap, 0.f);
        float m0 = p0 - x0, m1 = p1 - x1, m2 = p2 - x2, m3 = p3 - x3;
        float h0 = fmaxf(cap - m0, 0.f), h1 = fmaxf(cap - m1, 0.f);
        float h2 = fmaxf(cap - m2, 0.f), h3 = fmaxf(cap - m3, 0.f);
        float sx = x0 + x1 + x2 + x3;
        float sh = h0 + h1 + h2 + h3;
        #pragma unroll
        for (int off = 8; off >= 1; off >>= 1) {
            sx += __shfl_xor(sx, off);
            sh += __shfl_xor(sh, off);
        }
        sh = fmaxf(sh, 1e-8f);
        float sc = sx / sh;
        float c0 = m0 + sc * h0;
        float c1 = m1 + sc * h1;
        float c2 = m2 + sc * h2;
        float c3 = m3 + sc * h3;

        const int iA = c16, iB = c16 + 16, iC = c16 + 32, iD = c16 + 48;
        float v1, v2; int j1, j2;
        if (better(c0, iA, c1, iB)) { v1 = c0; j1 = iA; v2 = c1; j2 = iB; }
        else                        { v1 = c1; j1 = iB; v2 = c0; j2 = iA; }
        if (better(c2, iC, v1, j1))      { v2 = v1; j2 = j1; v1 = c2; j1 = iC; }
        else if (better(c2, iC, v2, j2)) { v2 = c2; j2 = iC; }
        if (better(c3, iD, v1, j1))      { v2 = v1; j2 = j1; v1 = c3; j1 = iD; }
        else if (better(c3, iD, v2, j2)) { v2 = c3; j2 = iD; }

        #pragma unroll
        for (int off = 1; off < 16; off <<= 1) {
            float w1 = __shfl_xor(v1, off); int k1 = __shfl_xor(j1, off);
            float w2 = __shfl_xor(v2, off); int k2 = __shfl_xor(j2, off);
            if (better(w1, k1, v1, j1)) {
                if (better(v1, j1, w2, k2)) { v2 = v1; j2 = j1; }
                else                        { v2 = w2; j2 = k2; }
                v1 = w1; j1 = k1;
            } else if (better(w1, k1, v2, j2)) {
                v2 = w1; j2 = k1;
            }
        }

        float g0 = (iA == j1 || iA == j2) ? c0 : 0.f;
        float g1 = (iB == j1 || iB == j2) ? c1 : 0.f;
        float g2 = (iC == j1 || iC == j2) ? c2 : 0.f;
        float g3 = (iD == j1 || iD == j2) ? c3 : 0.f;

        float t0 = (iA == j1 || iA == j2) ? -3.0e38f : c0;
        float t1 = (iB == j1 || iB == j2) ? -3.0e38f : c1;
        float t2 = (iC == j1 || iC == j2) ? -3.0e38f : c2;
        float t3 = (iD == j1 || iD == j2) ? -3.0e38f : c3;
        float m3v = fmaxf(fmaxf(t0, t1), fmaxf(t2, t3));
        #pragma unroll
        for (int off = 8; off >= 1; off >>= 1)
            m3v = fmaxf(m3v, __shfl_xor(m3v, off));

        const int tl = wave * 16 + quad * 4 + r;
        bool flag = ((v2 - m3v) < 1e-4f) || (sx > 0.0f);
        if (flag && c16 == 0) {
            int pos = atomicAdd(flagCount, 1);
            if (pos < listCap) flagList[pos] = tokenBase + tl;
        }

        gtile[tl * 64 + iA] = g0;
        gtile[tl * 64 + iB] = g1;
        gtile[tl * 64 + iC] = g2;
        gtile[tl * 64 + iD] = g3;
    }

    __syncthreads();

    const uint4* src = reinterpret_cast<const uint4*>(gtile);
    uint4* dst = reinterpret_cast<uint4*>(out + (size_t)tokenBase * 64);
    dst[threadIdx.x]       = src[threadIdx.x];
    dst[threadIdx.x + 256] = src[threadIdx.x + 256];
    dst[threadIdx.x + 512] = src[threadIdx.x + 512];
    dst[threadIdx.x + 768] = src[threadIdx.x + 768];
}

// ---------------------------------------------------------------------------
// fp64 exact recompute of flagged tokens — batched: 8 tokens share one W pass.
// Token vectors staged in LDS; W read once per 8 tokens (was: once per token).
// ---------------------------------------------------------------------------
__global__ __launch_bounds__(256)
void repair_kernel(const float* __restrict__ tokens,
                   const int* __restrict__ tarr,
                   const float* __restrict__ Wg,
                   const float* __restrict__ bg,
                   float* __restrict__ out,
                   const int* __restrict__ cnt,
                   const int* __restrict__ list,
                   int listCap)
{
    __shared__ __align__(16) float atile[8][1024];   // 32 KB
    __shared__ double red[256];                      //  2 KB
    int count = cnt[0];
    if (count > listCap) count = listCap;

    const int e    = threadIdx.x & 63;   // expert
    const int part = threadIdx.x >> 6;   // k-quarter

    for (int base = blockIdx.x * 8; base < count; base += gridDim.x * 8) {
        const int n = min(8, count - base);

        // stage up to 8 token vectors (4 KB each) into LDS, fully coalesced
        #pragma unroll
        for (int t = 0; t < 8; ++t) {
            if (t < n) {
                const float4* src =
                    reinterpret_cast<const float4*>(tokens + (size_t)list[base + t] * 1024);
                reinterpret_cast<float4*>(atile[t])[threadIdx.x] = src[threadIdx.x];
            }
        }
        __syncthreads();

        // one W stream feeds all 8 tokens; per-thread W reads are sequential
        double acc0 = 0.0, acc1 = 0.0, acc2 = 0.0, acc3 = 0.0;
        double acc4 = 0.0, acc5 = 0.0, acc6 = 0.0, acc7 = 0.0;
        const float* wrow = Wg + (size_t)e * 1024 + part * 256;
        const int ko = part * 256;
        for (int k = 0; k < 256; k += 4) {
            float4 wv = *reinterpret_cast<const float4*>(wrow + k);
            const double w0 = (double)wv.x, w1 = (double)wv.y;
            const double w2 = (double)wv.z, w3 = (double)wv.w;
            #define ACC(T, A)                                                   \
                A = fma((double)atile[T][ko + k    ], w0, A);                    \
                A = fma((double)atile[T][ko + k + 1], w1, A);                    \
                A = fma((double)atile[T][ko + k + 2], w2, A);                    \
                A = fma((double)atile[T][ko + k + 3], w3, A);
            ACC(0, acc0) ACC(1, acc1) ACC(2, acc2) ACC(3, acc3)
            ACC(4, acc4) ACC(5, acc5) ACC(6, acc6) ACC(7, acc7)
            #undef ACC
        }

        #pragma unroll
        for (int t = 0; t < 8; ++t) {
            if (t >= n) break;   // n uniform across block: all threads break together
            double accT = (t == 0) ? acc0 : (t == 1) ? acc1 : (t == 2) ? acc2 :
                          (t == 3) ? acc3 : (t == 4) ? acc4 : (t == 5) ? acc5 :
                          (t == 6) ? acc6 : acc7;
            red[threadIdx.x] = accT;
            __syncthreads();

            if (threadIdx.x < 64) {   // one full wave does the fp64 epilogue
                const int token = list[base + t];
                double l = ((red[e] + red[64 + e]) + (red[128 + e] + red[192 + e]))
                         + (double)bg[e];

                double mxv = l;
                #pragma unroll
                for (int off = 32; off >= 1; off >>= 1)
                    mxv = fmax(mxv, __shfl_xor(mxv, off));
                double ex = exp(l - mxv);
                double s = ex;
                #pragma unroll
                for (int off = 32; off >= 1; off >>= 1)
                    s += __shfl_xor(s, off);

                const double alpha = 0.15;
                double p = (1.0 - alpha) * (ex / s) + alpha / 64.0;

                double tb  = (double)tarr[token >> 12];
                double capv = 0.5 + (0.6 + 0.5) * (tb / 1000.0);
                double x = fmax(p - capv, 0.0);
                double m = p - x;
                double h = fmax(capv - m, 0.0);
                double sx = x, sh = h;
                #pragma unroll
                for (int off = 32; off >= 1; off >>= 1) {
                    sx += __shfl_xor(sx, off);
                    sh += __shfl_xor(sh, off);
                }
                sh = fmax(sh, 1e-8);
                double c = m + (sx / sh) * h;

                double v1 = c, v2 = -1.0e300;
                int j1 = e, j2 = 127;
                #pragma unroll
                for (int off = 1; off < 64; off <<= 1) {
                    double w1 = __shfl_xor(v1, off); int k1 = __shfl_xor(j1, off);
                    double w2 = __shfl_xor(v2, off); int k2 = __shfl_xor(j2, off);
                    if (betterd(w1, k1, v1, j1)) {
                        if (betterd(v1, j1, w2, k2)) { v2 = v1; j2 = j1; }
                        else                         { v2 = w2; j2 = k2; }
                        v1 = w1; j1 = k1;
                    } else if (betterd(w1, k1, v2, j2)) {
                        v2 = w1; j2 = k1;
                    }
                }

                float g = (e == j1 || e == j2) ? (float)c : 0.0f;
                out[(size_t)token * 64 + e] = g;
            }
            __syncthreads();
        }
    }
}

extern "C" void kernel_launch(void* const* d_in, const int* in_sizes, int n_in,
                              void* d_out, int out_size, void* d_ws, size_t ws_size,
                              hipStream_t stream) {
    const float* tokens = (const float*)d_in[0];
    const int*   t      = (const int*)d_in[1];
    const float* Wg     = (const float*)d_in[2];
    const float* bg     = (const float*)d_in[3];
    float*       outp   = (float*)d_out;

    int* wsI = (int*)d_ws;
    const long long wsInts = (long long)(ws_size / 4);

    // pre-split layout: [0..15] counter | [16 ..) whi 128KB | wlo 128KB | flagList
    const int  WHALF   = 32768;                  // ints per bf16 half (64*1024 shorts)
    const long long listOff = 16 + 2LL * WHALF;  // = 65552 ints
    long long cap = wsInts - listOff;
    if (cap > 65536) cap = 65536;

    hipMemsetAsync(d_ws, 0, 64, stream);   // zero flag counter (capturable)

    if (cap >= 32768) {
        short* whi  = (short*)(wsI + 16);
        short* wlo  = (short*)(wsI + 16 + WHALF);
        int*   list = wsI + listOff;
        wsplit_kernel<<<dim3(64), dim3(256), 0, stream>>>(Wg, whi, wlo);
        router_kernel<<<dim3(65536 / 64), dim3(256), 0, stream>>>(
            tokens, t, bg, outp, wsI, list, (int)cap, whi, wlo);
        repair_kernel<<<dim3(256), dim3(256), 0, stream>>>(
            tokens, t, Wg, bg, outp, wsI, list, (int)cap);
    } else {
        long long cap2 = wsInts - 16;
        if (cap2 < 0) cap2 = 0;
        if (cap2 > 65536) cap2 = 65536;
        router_kernel_legacy<<<dim3(65536 / 64), dim3(256), 0, stream>>>(
            tokens, t, Wg, bg, outp, wsI, wsI + 16, (int)cap2);
        repair_kernel<<<dim3(256), dim3(256), 0, stream>>>(
            tokens, t, Wg, bg, outp, wsI, wsI + 16, (int)cap2);
    }
}

// Round 2
// 445.331 us; speedup vs baseline: 1.1274x; 1.1274x over previous
//
#include <hip/hip_runtime.h>
#include <hip/hip_bf16.h>

typedef __attribute__((ext_vector_type(8))) short short8;   // 8 x bf16 = 4 VGPRs
typedef __attribute__((ext_vector_type(4))) short sh4;      // 4 x bf16 = 8 bytes
typedef __attribute__((ext_vector_type(4))) float floatx4;  // MFMA C/D

// total ordering: larger value wins; tie -> smaller index wins (jax.lax.top_k)
__device__ __forceinline__ bool better(float va, int ia, float vb, int ib) {
    return (va > vb) || (va == vb && ia < ib);
}
__device__ __forceinline__ bool betterd(double va, int ia, double vb, int ib) {
    return (va > vb) || (va == vb && ia < ib);
}

__device__ __forceinline__ short bf16_rn(float f) {
    __hip_bfloat16 h = __float2bfloat16(f);   // round-to-nearest-even
    return *reinterpret_cast<short*>(&h);
}
__device__ __forceinline__ float bf16_up(short s) {
    return __uint_as_float(((unsigned)(unsigned short)s) << 16);
}

// split 8 fp32 into bf16 hi + bf16 lo fragments (a ~= hi + lo)
__device__ __forceinline__ void split8(float4 a, float4 b, short8& hi, short8& lo) {
    float v[8] = {a.x, a.y, a.z, a.w, b.x, b.y, b.z, b.w};
    #pragma unroll
    for (int i = 0; i < 8; ++i) {
        short h = bf16_rn(v[i]);
        hi[i] = h;
        lo[i] = bf16_rn(v[i] - bf16_up(h));
    }
}

#define MFMA(A, B, C) __builtin_amdgcn_mfma_f32_16x16x32_bf16((A), (B), (C), 0, 0, 0)

// async global -> LDS, 16B per lane.  LDS dest = wave-uniform base + lane*16.
__device__ __forceinline__ void gload16(const void* g, void* l) {
    __builtin_amdgcn_global_load_lds(
        (const __attribute__((address_space(1))) void*)g,
        (__attribute__((address_space(3))) void*)l,
        16, 0, 0);
}

// ---------------------------------------------------------------------------
// Prep: split W (64x1024 fp32) into bf16 hi/lo once.  64 blocks x 256 thr x 4.
// ---------------------------------------------------------------------------
__global__ __launch_bounds__(256)
void wsplit_kernel(const float* __restrict__ Wg,
                   short* __restrict__ whi,
                   short* __restrict__ wlo)
{
    const int i = blockIdx.x * 256 + threadIdx.x;       // 16384 float4s
    float4 v = reinterpret_cast<const float4*>(Wg)[i];
    float vv[4] = {v.x, v.y, v.z, v.w};
    sh4 h, l;
    #pragma unroll
    for (int j = 0; j < 4; ++j) {
        short hh = bf16_rn(vv[j]);
        h[j] = hh;
        l[j] = bf16_rn(vv[j] - bf16_up(hh));
    }
    reinterpret_cast<sh4*>(whi)[i] = h;
    reinterpret_cast<sh4*>(wlo)[i] = l;
}

// ---------------------------------------------------------------------------
// Main router: async double-buffered LDS pipeline.
//   chunk = 64 k-floats; A-chunk 16KB + Whi 8KB + Wlo 8KB = 32KB/buffer.
//   2 buffers + 16KB gtile = 80KB LDS -> 2 blocks/CU.
//   Per chunk per wave: 8 global_load_lds (1KB each); counted vmcnt(8) keeps
//   the next chunk's loads in flight across the barrier (never drain mid-loop).
//   Row-XOR swizzle (byte ^= (row&7)<<4) applied on the pre-swizzled global
//   source AND the ds_read address (both-sides-or-neither rule).
// Numerics identical to previous round: same splits, same MFMA order.
// ---------------------------------------------------------------------------
__global__ __launch_bounds__(256, 2)
void router_kernel(const float* __restrict__ tokens,
                   const int* __restrict__ tarr,
                   const float* __restrict__ bg,
                   float* __restrict__ out,
                   int* __restrict__ flagCount,
                   int* __restrict__ flagList,
                   int listCap,
                   const short* __restrict__ whi,
                   const short* __restrict__ wlo)
{
    __shared__ __align__(16) float gtile[64 * 64];       // 16 KB
    __shared__ __align__(16) char  stage[2][32768];      // 64 KB (A | Whi | Wlo)
    const int A_OFF = 0, WH_OFF = 16384, WL_OFF = 24576;

    const int lane = threadIdx.x & 63;
    const int wave = threadIdx.x >> 6;
    const int c16  = lane & 15;   // token-within-wave (A row) / expert-within-group (B row)
    const int quad = lane >> 4;   // k-chunk selector

    const int tokenBase = blockIdx.x * 64;

    // ---- per-lane staging source pointers (chunk 0); step per chunk -------
    const char* tokB = (const char*)tokens;
    const char* whiB = (const char*)whi;
    const char* wloB = (const char*)wlo;

    const char* aSrc[4];
    #pragma unroll
    for (int j = 0; j < 4; ++j) {
        const int row = 16 * wave + 4 * j + (lane >> 4);           // its OWN tokens
        const int v   = ((lane & 15) * 16) ^ ((row & 7) << 4);     // pre-swizzled src
        aSrc[j] = tokB + (size_t)(tokenBase + row) * 4096 + v;
    }
    const char* hSrc[2]; const char* lSrc[2];
    #pragma unroll
    for (int j = 0; j < 2; ++j) {
        const int e = 16 * wave + 8 * j + (lane >> 3);
        const int v = ((lane & 7) * 16) ^ ((e & 7) << 4);
        hSrc[j] = whiB + (size_t)e * 2048 + v;
        lSrc[j] = wloB + (size_t)e * 2048 + v;
    }

    floatx4 acc0 = {0.f, 0.f, 0.f, 0.f};
    floatx4 acc1 = acc0, acc2 = acc0, acc3 = acc0;

    const int r  = wave * 16 + c16;        // A row this lane reads
    const int sw = (c16 & 7) << 4;         // read-side swizzle (row&7 == c16&7)

    // ---- stage chunk 0 ----------------------------------------------------
    {
        char* b = stage[0];
        #pragma unroll
        for (int j = 0; j < 4; ++j) gload16(aSrc[j], b + A_OFF + (wave * 4 + j) * 1024);
        #pragma unroll
        for (int j = 0; j < 2; ++j) gload16(hSrc[j], b + WH_OFF + (wave * 2 + j) * 1024);
        #pragma unroll
        for (int j = 0; j < 2; ++j) gload16(lSrc[j], b + WL_OFF + (wave * 2 + j) * 1024);
    }

    int p = 0;
    for (int c = 0; c < 16; ++c) {
        // ---- stage chunk c+1 into the other buffer (async, stays in flight)
        if (c < 15) {
            char* b = stage[p ^ 1];
            const int co = (c + 1) * 256;   // A bytes per chunk
            const int cw = (c + 1) * 128;   // W bytes per chunk
            #pragma unroll
            for (int j = 0; j < 4; ++j) gload16(aSrc[j] + co, b + A_OFF + (wave * 4 + j) * 1024);
            #pragma unroll
            for (int j = 0; j < 2; ++j) gload16(hSrc[j] + cw, b + WH_OFF + (wave * 2 + j) * 1024);
            #pragma unroll
            for (int j = 0; j < 2; ++j) gload16(lSrc[j] + cw, b + WL_OFF + (wave * 2 + j) * 1024);
            asm volatile("s_waitcnt vmcnt(8)" ::: "memory");   // chunk c done; c+1 in flight
        } else {
            asm volatile("s_waitcnt vmcnt(0)" ::: "memory");   // last chunk: drain
        }
        __builtin_amdgcn_s_barrier();
        asm volatile("" ::: "memory");

        // ---- compute chunk c from buffer p ---------------------------------
        const char* bA = stage[p] + A_OFF;
        const char* bH = stage[p] + WH_OFF;
        const char* bL = stage[p] + WL_OFF;
        #pragma unroll
        for (int kb = 0; kb < 2; ++kb) {
            float4 a0 = *(const float4*)(bA + r * 256 + ((kb * 128 + quad * 32 +  0) ^ sw));
            float4 a1 = *(const float4*)(bA + r * 256 + ((kb * 128 + quad * 32 + 16) ^ sw));
            const int wu = (kb * 64 + quad * 16) ^ sw;
            short8 h0 = *(const short8*)(bH + (c16 +  0) * 128 + wu);
            short8 h1 = *(const short8*)(bH + (c16 + 16) * 128 + wu);
            short8 h2 = *(const short8*)(bH + (c16 + 32) * 128 + wu);
            short8 h3 = *(const short8*)(bH + (c16 + 48) * 128 + wu);
            short8 l0 = *(const short8*)(bL + (c16 +  0) * 128 + wu);
            short8 l1 = *(const short8*)(bL + (c16 + 16) * 128 + wu);
            short8 l2 = *(const short8*)(bL + (c16 + 32) * 128 + wu);
            short8 l3 = *(const short8*)(bL + (c16 + 48) * 128 + wu);

            short8 ahi, alo;
            split8(a0, a1, ahi, alo);

            acc0 = MFMA(ahi, h0, acc0); acc0 = MFMA(alo, h0, acc0); acc0 = MFMA(ahi, l0, acc0);
            acc1 = MFMA(ahi, h1, acc1); acc1 = MFMA(alo, h1, acc1); acc1 = MFMA(ahi, l1, acc1);
            acc2 = MFMA(ahi, h2, acc2); acc2 = MFMA(alo, h2, acc2); acc2 = MFMA(ahi, l2, acc2);
            acc3 = MFMA(ahi, h3, acc3); acc3 = MFMA(alo, h3, acc3); acc3 = MFMA(ahi, l3, acc3);
        }

        __builtin_amdgcn_s_barrier();     // all waves done reading p before it's restaged
        asm volatile("" ::: "memory");
        p ^= 1;
    }

    const float b0f = bg[c16 +  0];
    const float b1f = bg[c16 + 16];
    const float b2f = bg[c16 + 32];
    const float b3f = bg[c16 + 48];

    const float tb  = (float)tarr[tokenBase >> 12];   // 4096 tokens per batch
    const float cap = 0.5f + 1.1f * (tb / 1000.0f);

    const float A1 = 0.85f;            // 1 - alpha, alpha = 0.15
    const float A2 = 0.15f / 64.0f;    // alpha / E

    #pragma unroll
    for (int rr = 0; rr < 4; ++rr) {
        float l0 = acc0[rr] + b0f;
        float l1 = acc1[rr] + b1f;
        float l2 = acc2[rr] + b2f;
        float l3 = acc3[rr] + b3f;

        // --- softmax over 64 experts (16-lane group x 4 local) ---
        float mx = fmaxf(fmaxf(l0, l1), fmaxf(l2, l3));
        #pragma unroll
        for (int off = 8; off >= 1; off >>= 1)
            mx = fmaxf(mx, __shfl_xor(mx, off));

        float e0 = expf(l0 - mx), e1 = expf(l1 - mx);
        float e2 = expf(l2 - mx), e3 = expf(l3 - mx);
        float s = e0 + e1 + e2 + e3;
        #pragma unroll
        for (int off = 8; off >= 1; off >>= 1)
            s += __shfl_xor(s, off);
        float inv = 1.0f / s;

        // --- routing floor ---
        float p0 = A1 * (e0 * inv) + A2;
        float p1 = A1 * (e1 * inv) + A2;
        float p2 = A1 * (e2 * inv) + A2;
        float p3 = A1 * (e3 * inv) + A2;

        // --- hard cap with excess redistribution ---
        float x0 = fmaxf(p0 - cap, 0.f), x1 = fmaxf(p1 - cap, 0.f);
        float x2 = fmaxf(p2 - cap, 0.f), x3 = fmaxf(p3 - cap, 0.f);
        float m0 = p0 - x0, m1 = p1 - x1, m2 = p2 - x2, m3 = p3 - x3;
        float h0 = fmaxf(cap - m0, 0.f), h1 = fmaxf(cap - m1, 0.f);
        float h2 = fmaxf(cap - m2, 0.f), h3 = fmaxf(cap - m3, 0.f);
        float sx = x0 + x1 + x2 + x3;
        float sh = h0 + h1 + h2 + h3;
        #pragma unroll
        for (int off = 8; off >= 1; off >>= 1) {
            sx += __shfl_xor(sx, off);
            sh += __shfl_xor(sh, off);
        }
        sh = fmaxf(sh, 1e-8f);
        float sc = sx / sh;
        float c0 = m0 + sc * h0;
        float c1 = m1 + sc * h1;
        float c2 = m2 + sc * h2;
        float c3 = m3 + sc * h3;

        // --- top-2 (value desc, tie -> smaller expert index) ---
        const int iA = c16, iB = c16 + 16, iC = c16 + 32, iD = c16 + 48;
        float v1, v2; int j1, j2;
        if (better(c0, iA, c1, iB)) { v1 = c0; j1 = iA; v2 = c1; j2 = iB; }
        else                        { v1 = c1; j1 = iB; v2 = c0; j2 = iA; }
        if (better(c2, iC, v1, j1))      { v2 = v1; j2 = j1; v1 = c2; j1 = iC; }
        else if (better(c2, iC, v2, j2)) { v2 = c2; j2 = iC; }
        if (better(c3, iD, v1, j1))      { v2 = v1; j2 = j1; v1 = c3; j1 = iD; }
        else if (better(c3, iD, v2, j2)) { v2 = c3; j2 = iD; }

        #pragma unroll
        for (int off = 1; off < 16; off <<= 1) {
            float w1 = __shfl_xor(v1, off); int k1 = __shfl_xor(j1, off);
            float w2 = __shfl_xor(v2, off); int k2 = __shfl_xor(j2, off);
            if (better(w1, k1, v1, j1)) {
                if (better(v1, j1, w2, k2)) { v2 = v1; j2 = j1; }
                else                        { v2 = w2; j2 = k2; }
                v1 = w1; j1 = k1;
            } else if (better(w1, k1, v2, j2)) {
                v2 = w1; j2 = k1;
            }
        }

        float g0 = (iA == j1 || iA == j2) ? c0 : 0.f;
        float g1 = (iB == j1 || iB == j2) ? c1 : 0.f;
        float g2 = (iC == j1 || iC == j2) ? c2 : 0.f;
        float g3 = (iD == j1 || iD == j2) ? c3 : 0.f;

        // --- rank2 vs rank3 margin; flag uncertain tokens for fp64 repair ---
        float t0 = (iA == j1 || iA == j2) ? -3.0e38f : c0;
        float t1 = (iB == j1 || iB == j2) ? -3.0e38f : c1;
        float t2 = (iC == j1 || iC == j2) ? -3.0e38f : c2;
        float t3 = (iD == j1 || iD == j2) ? -3.0e38f : c3;
        float m3v = fmaxf(fmaxf(t0, t1), fmaxf(t2, t3));
        #pragma unroll
        for (int off = 8; off >= 1; off >>= 1)
            m3v = fmaxf(m3v, __shfl_xor(m3v, off));

        const int tl = wave * 16 + quad * 4 + rr;   // token within block
        bool flag = ((v2 - m3v) < 1e-4f) || (sx > 0.0f);
        if (flag && c16 == 0) {
            int pos = atomicAdd(flagCount, 1);
            if (pos < listCap) flagList[pos] = tokenBase + tl;
        }

        gtile[tl * 64 + iA] = g0;
        gtile[tl * 64 + iB] = g1;
        gtile[tl * 64 + iC] = g2;
        gtile[tl * 64 + iD] = g3;
    }

    __syncthreads();

    const uint4* src = reinterpret_cast<const uint4*>(gtile);
    uint4* dst = reinterpret_cast<uint4*>(out + (size_t)tokenBase * 64);
    dst[threadIdx.x]       = src[threadIdx.x];
    dst[threadIdx.x + 256] = src[threadIdx.x + 256];
    dst[threadIdx.x + 512] = src[threadIdx.x + 512];
    dst[threadIdx.x + 768] = src[threadIdx.x + 768];
}

// ---------------------------------------------------------------------------
// Legacy router (inline W split) — fallback when workspace is too small for
// the pre-split W area.  Identical to the originally verified kernel.
// ---------------------------------------------------------------------------
__global__ __launch_bounds__(256, 4)
void router_kernel_legacy(const float* __restrict__ tokens,
                          const int* __restrict__ tarr,
                          const float* __restrict__ Wg,
                          const float* __restrict__ bg,
                          float* __restrict__ out,
                          int* __restrict__ flagCount,
                          int* __restrict__ flagList,
                          int listCap)
{
    __shared__ __align__(16) float gtile[64 * 64];

    const int lane = threadIdx.x & 63;
    const int wave = threadIdx.x >> 6;
    const int c16  = lane & 15;
    const int quad = lane >> 4;

    const int tokenBase = blockIdx.x * 64;
    const int token     = tokenBase + wave * 16 + c16;

    const float4* ap = reinterpret_cast<const float4*>(tokens) + (size_t)token * 256 + quad * 2;
    const float4* wp0 = reinterpret_cast<const float4*>(Wg) + (size_t)(c16 +  0) * 256 + quad * 2;
    const float4* wp1 = reinterpret_cast<const float4*>(Wg) + (size_t)(c16 + 16) * 256 + quad * 2;
    const float4* wp2 = reinterpret_cast<const float4*>(Wg) + (size_t)(c16 + 32) * 256 + quad * 2;
    const float4* wp3 = reinterpret_cast<const float4*>(Wg) + (size_t)(c16 + 48) * 256 + quad * 2;

    floatx4 acc0 = {0.f, 0.f, 0.f, 0.f};
    floatx4 acc1 = acc0, acc2 = acc0, acc3 = acc0;

    for (int kb = 0; kb < 32; ++kb) {
        short8 ahi, alo;
        split8(ap[kb * 8], ap[kb * 8 + 1], ahi, alo);
        {
            short8 whi, wlo;
            split8(wp0[kb * 8], wp0[kb * 8 + 1], whi, wlo);
            acc0 = MFMA(ahi, whi, acc0);
            acc0 = MFMA(alo, whi, acc0);
            acc0 = MFMA(ahi, wlo, acc0);
        }
        {
            short8 whi, wlo;
            split8(wp1[kb * 8], wp1[kb * 8 + 1], whi, wlo);
            acc1 = MFMA(ahi, whi, acc1);
            acc1 = MFMA(alo, whi, acc1);
            acc1 = MFMA(ahi, wlo, acc1);
        }
        {
            short8 whi, wlo;
            split8(wp2[kb * 8], wp2[kb * 8 + 1], whi, wlo);
            acc2 = MFMA(ahi, whi, acc2);
            acc2 = MFMA(alo, whi, acc2);
            acc2 = MFMA(ahi, wlo, acc2);
        }
        {
            short8 whi, wlo;
            split8(wp3[kb * 8], wp3[kb * 8 + 1], whi, wlo);
            acc3 = MFMA(ahi, whi, acc3);
            acc3 = MFMA(alo, whi, acc3);
            acc3 = MFMA(ahi, wlo, acc3);
        }
    }

    const float b0f = bg[c16 +  0];
    const float b1f = bg[c16 + 16];
    const float b2f = bg[c16 + 32];
    const float b3f = bg[c16 + 48];

    const float tb  = (float)tarr[tokenBase >> 12];
    const float cap = 0.5f + 1.1f * (tb / 1000.0f);

    const float A1 = 0.85f;
    const float A2 = 0.15f / 64.0f;

    #pragma unroll
    for (int r = 0; r < 4; ++r) {
        float l0 = acc0[r] + b0f;
        float l1 = acc1[r] + b1f;
        float l2 = acc2[r] + b2f;
        float l3 = acc3[r] + b3f;

        float mx = fmaxf(fmaxf(l0, l1), fmaxf(l2, l3));
        #pragma unroll
        for (int off = 8; off >= 1; off >>= 1)
            mx = fmaxf(mx, __shfl_xor(mx, off));

        float e0 = expf(l0 - mx), e1 = expf(l1 - mx);
        float e2 = expf(l2 - mx), e3 = expf(l3 - mx);
        float s = e0 + e1 + e2 + e3;
        #pragma unroll
        for (int off = 8; off >= 1; off >>= 1)
            s += __shfl_xor(s, off);
        float inv = 1.0f / s;

        float p0 = A1 * (e0 * inv) + A2;
        float p1 = A1 * (e1 * inv) + A2;
        float p2 = A1 * (e2 * inv) + A2;
        float p3 = A1 * (e3 * inv) + A2;

        float x0 = fmaxf(p0 - cap, 0.f), x1 = fmaxf(p1 - cap, 0.f);
        float x2 = fmaxf(p2 - cap, 0.f), x3 = fmaxf(p3 - cap, 0.f);
        float m0 = p0 - x0, m1 = p1 - x1, m2 = p2 - x2, m3 = p3 - x3;
        float h0 = fmaxf(cap - m0, 0.f), h1 = fmaxf(cap - m1, 0.f);
        float h2 = fmaxf(cap - m2, 0.f), h3 = fmaxf(cap - m3, 0.f);
        float sx = x0 + x1 + x2 + x3;
        float sh = h0 + h1 + h2 + h3;
        #pragma unroll
        for (int off = 8; off >= 1; off >>= 1) {
            sx += __shfl_xor(sx, off);
            sh += __shfl_xor(sh, off);
        }
        sh = fmaxf(sh, 1e-8f);
        float sc = sx / sh;
        float c0 = m0 + sc * h0;
        float c1 = m1 + sc * h1;
        float c2 = m2 + sc * h2;
        float c3 = m3 + sc * h3;

        const int iA = c16, iB = c16 + 16, iC = c16 + 32, iD = c16 + 48;
        float v1, v2; int j1, j2;
        if (better(c0, iA, c1, iB)) { v1 = c0; j1 = iA; v2 = c1; j2 = iB; }
        else                        { v1 = c1; j1 = iB; v2 = c0; j2 = iA; }
        if (better(c2, iC, v1, j1))      { v2 = v1; j2 = j1; v1 = c2; j1 = iC; }
        else if (better(c2, iC, v2, j2)) { v2 = c2; j2 = iC; }
        if (better(c3, iD, v1, j1))      { v2 = v1; j2 = j1; v1 = c3; j1 = iD; }
        else if (better(c3, iD, v2, j2)) { v2 = c3; j2 = iD; }

        #pragma unroll
        for (int off = 1; off < 16; off <<= 1) {
            float w1 = __shfl_xor(v1, off); int k1 = __shfl_xor(j1, off);
            float w2 = __shfl_xor(v2, off); int k2 = __shfl_xor(j2, off);
            if (better(w1, k1, v1, j1)) {
                if (better(v1, j1, w2, k2)) { v2 = v1; j2 = j1; }
                else                        { v2 = w2; j2 = k2; }
                v1 = w1; j1 = k1;
            } else if (better(w1, k1, v2, j2)) {
                v2 = w1; j2 = k1;
            }
        }

        float g0 = (iA == j1 || iA == j2) ? c0 : 0.f;
        float g1 = (iB == j1 || iB == j2) ? c1 : 0.f;
        float g2 = (iC == j1 || iC == j2) ? c2 : 0.f;
        float g3 = (iD == j1 || iD == j2) ? c3 : 0.f;

        float t0 = (iA == j1 || iA == j2) ? -3.0e38f : c0;
        float t1 = (iB == j1 || iB == j2) ? -3.0e38f : c1;
        float t2 = (iC == j1 || iC == j2) ? -3.0e38f : c2;
        float t3 = (iD == j1 || iD == j2) ? -3.0e38f : c3;
        float m3v = fmaxf(fmaxf(t0, t1), fmaxf(t2, t3));
        #pragma unroll
        for (int off = 8; off >= 1; off >>= 1)
            m3v = fmaxf(m3v, __shfl_xor(m3v, off));

        const int tl = wave * 16 + quad * 4 + r;
        bool flag = ((v2 - m3v) < 1e-4f) || (sx > 0.0f);
        if (flag && c16 == 0) {
            int pos = atomicAdd(flagCount, 1);
            if (pos < listCap) flagList[pos] = tokenBase + tl;
        }

        gtile[tl * 64 + iA] = g0;
        gtile[tl * 64 + iB] = g1;
        gtile[tl * 64 + iC] = g2;
        gtile[tl * 64 + iD] = g3;
    }

    __syncthreads();

    const uint4* src = reinterpret_cast<const uint4*>(gtile);
    uint4* dst = reinterpret_cast<uint4*>(out + (size_t)tokenBase * 64);
    dst[threadIdx.x]       = src[threadIdx.x];
    dst[threadIdx.x + 256] = src[threadIdx.x + 256];
    dst[threadIdx.x + 512] = src[threadIdx.x + 512];
    dst[threadIdx.x + 768] = src[threadIdx.x + 768];
}

// ---------------------------------------------------------------------------
// fp64 exact recompute of flagged tokens — batched: 8 tokens share one W pass.
// ---------------------------------------------------------------------------
__global__ __launch_bounds__(256)
void repair_kernel(const float* __restrict__ tokens,
                   const int* __restrict__ tarr,
                   const float* __restrict__ Wg,
                   const float* __restrict__ bg,
                   float* __restrict__ out,
                   const int* __restrict__ cnt,
                   const int* __restrict__ list,
                   int listCap)
{
    __shared__ __align__(16) float atile[8][1024];   // 32 KB
    __shared__ double red[256];                      //  2 KB
    int count = cnt[0];
    if (count > listCap) count = listCap;

    const int e    = threadIdx.x & 63;   // expert
    const int part = threadIdx.x >> 6;   // k-quarter

    for (int base = blockIdx.x * 8; base < count; base += gridDim.x * 8) {
        const int n = min(8, count - base);

        #pragma unroll
        for (int t = 0; t < 8; ++t) {
            if (t < n) {
                const float4* src =
                    reinterpret_cast<const float4*>(tokens + (size_t)list[base + t] * 1024);
                reinterpret_cast<float4*>(atile[t])[threadIdx.x] = src[threadIdx.x];
            }
        }
        __syncthreads();

        double acc0 = 0.0, acc1 = 0.0, acc2 = 0.0, acc3 = 0.0;
        double acc4 = 0.0, acc5 = 0.0, acc6 = 0.0, acc7 = 0.0;
        const float* wrow = Wg + (size_t)e * 1024 + part * 256;
        const int ko = part * 256;
        for (int k = 0; k < 256; k += 4) {
            float4 wv = *reinterpret_cast<const float4*>(wrow + k);
            const double w0 = (double)wv.x, w1 = (double)wv.y;
            const double w2 = (double)wv.z, w3 = (double)wv.w;
            #define ACC(T, A)                                                   \
                A = fma((double)atile[T][ko + k    ], w0, A);                    \
                A = fma((double)atile[T][ko + k + 1], w1, A);                    \
                A = fma((double)atile[T][ko + k + 2], w2, A);                    \
                A = fma((double)atile[T][ko + k + 3], w3, A);
            ACC(0, acc0) ACC(1, acc1) ACC(2, acc2) ACC(3, acc3)
            ACC(4, acc4) ACC(5, acc5) ACC(6, acc6) ACC(7, acc7)
            #undef ACC
        }

        #pragma unroll
        for (int t = 0; t < 8; ++t) {
            if (t >= n) break;
            double accT = (t == 0) ? acc0 : (t == 1) ? acc1 : (t == 2) ? acc2 :
                          (t == 3) ? acc3 : (t == 4) ? acc4 : (t == 5) ? acc5 :
                          (t == 6) ? acc6 : acc7;
            red[threadIdx.x] = accT;
            __syncthreads();

            if (threadIdx.x < 64) {
                const int token = list[base + t];
                double l = ((red[e] + red[64 + e]) + (red[128 + e] + red[192 + e]))
                         + (double)bg[e];

                double mxv = l;
                #pragma unroll
                for (int off = 32; off >= 1; off >>= 1)
                    mxv = fmax(mxv, __shfl_xor(mxv, off));
                double ex = exp(l - mxv);
                double s = ex;
                #pragma unroll
                for (int off = 32; off >= 1; off >>= 1)
                    s += __shfl_xor(s, off);

                const double alpha = 0.15;
                double p = (1.0 - alpha) * (ex / s) + alpha / 64.0;

                double tb  = (double)tarr[token >> 12];
                double capv = 0.5 + (0.6 + 0.5) * (tb / 1000.0);
                double x = fmax(p - capv, 0.0);
                double m = p - x;
                double h = fmax(capv - m, 0.0);
                double sx = x, sh = h;
                #pragma unroll
                for (int off = 32; off >= 1; off >>= 1) {
                    sx += __shfl_xor(sx, off);
                    sh += __shfl_xor(sh, off);
                }
                sh = fmax(sh, 1e-8);
                double c = m + (sx / sh) * h;

                double v1 = c, v2 = -1.0e300;
                int j1 = e, j2 = 127;
                #pragma unroll
                for (int off = 1; off < 64; off <<= 1) {
                    double w1 = __shfl_xor(v1, off); int k1 = __shfl_xor(j1, off);
                    double w2 = __shfl_xor(v2, off); int k2 = __shfl_xor(j2, off);
                    if (betterd(w1, k1, v1, j1)) {
                        if (betterd(v1, j1, w2, k2)) { v2 = v1; j2 = j1; }
                        else                         { v2 = w2; j2 = k2; }
                        v1 = w1; j1 = k1;
                    } else if (betterd(w1, k1, v2, j2)) {
                        v2 = w1; j2 = k1;
                    }
                }

                float g = (e == j1 || e == j2) ? (float)c : 0.0f;
                out[(size_t)token * 64 + e] = g;
            }
            __syncthreads();
        }
    }
}

extern "C" void kernel_launch(void* const* d_in, const int* in_sizes, int n_in,
                              void* d_out, int out_size, void* d_ws, size_t ws_size,
                              hipStream_t stream) {
    const float* tokens = (const float*)d_in[0];
    const int*   t      = (const int*)d_in[1];
    const float* Wg     = (const float*)d_in[2];
    const float* bg     = (const float*)d_in[3];
    float*       outp   = (float*)d_out;

    int* wsI = (int*)d_ws;
    const long long wsInts = (long long)(ws_size / 4);

    // layout: [0..15] counter | [16 ..) whi 128KB | wlo 128KB | flagList
    const int  WHALF   = 32768;                  // ints per bf16 half (64*1024 shorts)
    const long long listOff = 16 + 2LL * WHALF;  // = 65552 ints
    long long cap = wsInts - listOff;
    if (cap > 65536) cap = 65536;

    hipMemsetAsync(d_ws, 0, 64, stream);   // zero flag counter (capturable)

    if (cap >= 32768) {
        short* whi  = (short*)(wsI + 16);
        short* wlo  = (short*)(wsI + 16 + WHALF);
        int*   list = wsI + listOff;
        wsplit_kernel<<<dim3(64), dim3(256), 0, stream>>>(Wg, whi, wlo);
        router_kernel<<<dim3(65536 / 64), dim3(256), 0, stream>>>(
            tokens, t, bg, outp, wsI, list, (int)cap, whi, wlo);
        repair_kernel<<<dim3(256), dim3(256), 0, stream>>>(
            tokens, t, Wg, bg, outp, wsI, list, (int)cap);
    } else {
        long long cap2 = wsInts - 16;
        if (cap2 < 0) cap2 = 0;
        if (cap2 > 65536) cap2 = 65536;
        router_kernel_legacy<<<dim3(65536 / 64), dim3(256), 0, stream>>>(
            tokens, t, Wg, bg, outp, wsI, wsI + 16, (int)cap2);
        repair_kernel<<<dim3(256), dim3(256), 0, stream>>>(
            tokens, t, Wg, bg, outp, wsI, wsI + 16, (int)cap2);
    }
}